// Round 1
// baseline (497.777 us; speedup 1.0000x reference)
//
#include <hip/hip_runtime.h>
#include <hip/hip_bf16.h>
#include <stdint.h>

#define BB 4
#define SQL 2048
#define SKL 2048
#define EMB 1024
#define NH 16
#define DH 64
// M = BB*SQL = 8192 rows for projections

typedef __bf16 bf16x8 __attribute__((ext_vector_type(8)));
typedef float f32x4 __attribute__((ext_vector_type(4)));

__device__ __forceinline__ unsigned short f2bf(float f) {
  union { float f; uint32_t u; } v; v.f = f;
  uint32_t u = v.u;
  return (unsigned short)((u + 0x7fffu + ((u >> 16) & 1u)) >> 16);
}

typedef const __attribute__((address_space(1))) void* gas_t;
typedef __attribute__((address_space(3))) void* las_t;
__device__ __forceinline__ void gld16(const void* g, void* l) {
  __builtin_amdgcn_global_load_lds((gas_t)g, (las_t)l, 16, 0, 0);
}

// ---------------- fp32 -> bf16 convert (vectorized) ----------------
__global__ void cvt_bf16_kernel(const float* __restrict__ src,
                                unsigned short* __restrict__ dst, int n4) {
  int i = blockIdx.x * 256 + threadIdx.x;
  if (i >= n4) return;
  float4 v = ((const float4*)src)[i];
  ushort4 o;
  o.x = f2bf(v.x); o.y = f2bf(v.y); o.z = f2bf(v.z); o.w = f2bf(v.w);
  ((ushort4*)dst)[i] = o;
}

// ---------------- w [K][N] fp32 -> w^T [N][K] bf16 ----------------
__global__ void wtrans_kernel(const float* __restrict__ w0, const float* __restrict__ w1,
                              const float* __restrict__ w2,
                              unsigned short* __restrict__ o0, unsigned short* __restrict__ o1,
                              unsigned short* __restrict__ o2) {
  __shared__ float t[32][33];
  const float* w = blockIdx.z == 0 ? w0 : (blockIdx.z == 1 ? w1 : w2);
  unsigned short* o = blockIdx.z == 0 ? o0 : (blockIdx.z == 1 ? o1 : o2);
  int tx = threadIdx.x & 31, ty = threadIdx.x >> 5;  // 32 x 8
  int n0 = blockIdx.x * 32, k0 = blockIdx.y * 32;
#pragma unroll
  for (int r = 0; r < 4; r++)
    t[ty + r * 8][tx] = w[(size_t)(k0 + ty + r * 8) * EMB + n0 + tx];
  __syncthreads();
#pragma unroll
  for (int r = 0; r < 4; r++)
    o[(size_t)(n0 + ty + r * 8) * EMB + k0 + tx] = f2bf(t[tx][ty + r * 8]);
}

// ---------------- mask int32 -> packed bits ----------------
__global__ void maskpack_kernel(const int* __restrict__ m, unsigned int* __restrict__ words) {
  int w = blockIdx.x * 256 + threadIdx.x;  // 4*2048*64 words
  const int4* p = (const int4*)(m + (size_t)w * 32);
  unsigned int bits = 0;
#pragma unroll
  for (int j = 0; j < 8; j++) {
    int4 v = p[j];
    bits |= (v.x != 0 ? 1u : 0u) << (j * 4 + 0);
    bits |= (v.y != 0 ? 1u : 0u) << (j * 4 + 1);
    bits |= (v.z != 0 ? 1u : 0u) << (j * 4 + 2);
    bits |= (v.w != 0 ? 1u : 0u) << (j * 4 + 3);
  }
  words[w] = bits;
}

// ---------------- projection GEMM: C = A[8192x1024] * Bt^T + bias ----------------
// MODE 0: out[bh][s][64] bf16 (Q,K).  MODE 1: out[bh][64][s] bf16 (V transposed).
template <int MODE>
__global__ __launch_bounds__(256, 2) void proj_gemm_kernel(
    const unsigned short* __restrict__ A,   // [8192][1024] bf16
    const unsigned short* __restrict__ Bt,  // [1024 n][1024 k] bf16
    const float* __restrict__ bias,         // [1024]
    unsigned short* __restrict__ out) {
  __shared__ short As[128 * 32];
  __shared__ short Bs[128 * 32];
  const int tid = threadIdx.x;
  const int wave = tid >> 6, lane = tid & 63;
  const int l15 = lane & 15, q4 = lane >> 4;
  const int wm = wave >> 1, wn = wave & 1;
  const int m0 = blockIdx.y * 128, n0 = blockIdx.x * 128;

  f32x4 acc[4][4];
#pragma unroll
  for (int i = 0; i < 4; i++)
#pragma unroll
    for (int j = 0; j < 4; j++) acc[i][j] = (f32x4){0.f, 0.f, 0.f, 0.f};

  const int r = tid >> 2;        // 0..63
  const int c = (tid & 3) * 8;   // 0,8,16,24
  const unsigned short* gA0 = A + (size_t)(m0 + r) * EMB + c;
  const unsigned short* gA1 = A + (size_t)(m0 + r + 64) * EMB + c;
  const unsigned short* gB0 = Bt + (size_t)(n0 + r) * EMB + c;
  const unsigned short* gB1 = Bt + (size_t)(n0 + r + 64) * EMB + c;
  short* lA0 = As + tid * 8;
  short* lA1 = As + tid * 8 + 2048;
  short* lB0 = Bs + tid * 8;
  short* lB1 = Bs + tid * 8 + 2048;

  for (int kt = 0; kt < EMB / 32; kt++) {
    __syncthreads();
    gld16(gA0 + kt * 32, lA0);
    gld16(gA1 + kt * 32, lA1);
    gld16(gB0 + kt * 32, lB0);
    gld16(gB1 + kt * 32, lB1);
    __syncthreads();
    bf16x8 a[4], b[4];
#pragma unroll
    for (int i = 0; i < 4; i++)
      a[i] = *(const bf16x8*)(As + (wm * 64 + i * 16 + l15) * 32 + q4 * 8);
#pragma unroll
    for (int j = 0; j < 4; j++)
      b[j] = *(const bf16x8*)(Bs + (wn * 64 + j * 16 + l15) * 32 + q4 * 8);
#pragma unroll
    for (int i = 0; i < 4; i++)
#pragma unroll
      for (int j = 0; j < 4; j++)
        acc[i][j] = __builtin_amdgcn_mfma_f32_16x16x32_bf16(a[i], b[j], acc[i][j], 0, 0, 0);
  }

  // epilogue: C row = m0+wm*64+i*16+q4*4+reg, col = n0+wn*64+j*16+l15
#pragma unroll
  for (int i = 0; i < 4; i++) {
    const int mrow = m0 + wm * 64 + i * 16 + q4 * 4;
#pragma unroll
    for (int j = 0; j < 4; j++) {
      const int n = n0 + wn * 64 + j * 16 + l15;
      const float bv = bias[n];
      const int h = n >> 6, d = n & 63;
      if (MODE == 0) {
#pragma unroll
        for (int rg = 0; rg < 4; rg++) {
          int m = mrow + rg;
          int bb = m >> 11, sq = m & 2047;
          out[(size_t)((bb * NH + h) * SQL + sq) * DH + d] = f2bf(acc[i][j][rg] + bv);
        }
      } else {
        int bb = mrow >> 11, sq = mrow & 2047;
        ushort4 pk;
        pk.x = f2bf(acc[i][j][0] + bv);
        pk.y = f2bf(acc[i][j][1] + bv);
        pk.z = f2bf(acc[i][j][2] + bv);
        pk.w = f2bf(acc[i][j][3] + bv);
        *(ushort4*)(out + (size_t)((bb * NH + h) * DH + d) * SKL + sq) = pk;
      }
    }
  }
}

// ---------------- fused flash attention ----------------
// grid (32 qtiles, 64 bh), 256 threads. wave -> 16 q rows. 64-kv chunks in LDS.
__global__ __launch_bounds__(256, 2) void attn_kernel(
    const unsigned short* __restrict__ Qb,  // [64][2048][64]
    const unsigned short* __restrict__ Kb,  // [64][2048][64]
    const unsigned short* __restrict__ Vt,  // [64][64][2048]
    const unsigned int* __restrict__ mw,    // [4][2048][64]
    float* __restrict__ out) {              // [4][2048][1024]
  __shared__ short Ks[64 * 64];       // [kv][d]
  __shared__ short Vs[64 * 64];       // [d][kv]
  __shared__ short Ps[4][16 * 80];    // per-wave P scratch, pitch 80 (bank-spread)
  const int tid = threadIdx.x;
  const int wave = tid >> 6, lane = tid & 63;
  const int l15 = lane & 15, q4 = lane >> 4;
  const int bh = blockIdx.y;
  const int b = bh >> 4, h = bh & 15;
  const int q0 = blockIdx.x * 64 + wave * 16;

  const unsigned short* qg = Qb + (size_t)(bh * SQL + q0 + l15) * DH + q4 * 8;
  bf16x8 qa0 = *(const bf16x8*)qg;
  bf16x8 qa1 = *(const bf16x8*)(qg + 32);

  f32x4 o[4];
#pragma unroll
  for (int j = 0; j < 4; j++) o[j] = (f32x4){0.f, 0.f, 0.f, 0.f};
  float mrow[4] = {-3e38f, -3e38f, -3e38f, -3e38f};
  float lrow[4] = {0.f, 0.f, 0.f, 0.f};  // per-lane partial row sums

  const unsigned short* kg = Kb + (size_t)bh * SKL * DH;
  const unsigned short* vg = Vt + (size_t)bh * DH * SKL;
  const int trow = tid >> 3;        // 0..31
  const int tcol = (tid & 7) * 8;   // 0..56
  short* lK0 = Ks + tid * 8; short* lK1 = Ks + tid * 8 + 2048;
  short* lV0 = Vs + tid * 8; short* lV1 = Vs + tid * 8 + 2048;

  for (int kv0 = 0; kv0 < SKL; kv0 += 64) {
    __syncthreads();
    gld16(kg + (size_t)(kv0 + trow) * DH + tcol, lK0);
    gld16(kg + (size_t)(kv0 + trow + 32) * DH + tcol, lK1);
    gld16(vg + (size_t)trow * SKL + kv0 + tcol, lV0);
    gld16(vg + (size_t)(trow + 32) * SKL + kv0 + tcol, lV1);
    __syncthreads();

    // S = Q * K^T : 4 kv-subtiles of 16
    f32x4 sacc[4];
#pragma unroll
    for (int s = 0; s < 4; s++) {
      bf16x8 k0f = *(const bf16x8*)(Ks + (s * 16 + l15) * 64 + q4 * 8);
      bf16x8 k1f = *(const bf16x8*)(Ks + (s * 16 + l15) * 64 + 32 + q4 * 8);
      f32x4 z4 = (f32x4){0.f, 0.f, 0.f, 0.f};
      z4 = __builtin_amdgcn_mfma_f32_16x16x32_bf16(qa0, k0f, z4, 0, 0, 0);
      sacc[s] = __builtin_amdgcn_mfma_f32_16x16x32_bf16(qa1, k1f, z4, 0, 0, 0);
    }

    const int wq_base = b * SQL + q0 + q4 * 4;
    uint2 mk[4];
#pragma unroll
    for (int rg = 0; rg < 4; rg++)
      mk[rg] = *(const uint2*)(mw + (size_t)(wq_base + rg) * 64 + (kv0 >> 5));

#pragma unroll
    for (int rg = 0; rg < 4; rg++) {
      float sv[4];
#pragma unroll
      for (int s = 0; s < 4; s++) {
        float x = sacc[s][rg] * 0.125f;
        unsigned int word = (s < 2) ? mk[rg].x : mk[rg].y;
        unsigned int bit = (word >> ((s & 1) * 16 + l15)) & 1u;
        sv[s] = bit ? -1e9f : x;
      }
      float cm = fmaxf(fmaxf(sv[0], sv[1]), fmaxf(sv[2], sv[3]));
      cm = fmaxf(cm, __shfl_xor(cm, 1));
      cm = fmaxf(cm, __shfl_xor(cm, 2));
      cm = fmaxf(cm, __shfl_xor(cm, 4));
      cm = fmaxf(cm, __shfl_xor(cm, 8));
      float mnew = fmaxf(mrow[rg], cm);
      float alpha = __expf(mrow[rg] - mnew);
      mrow[rg] = mnew;
      float psum = 0.f;
#pragma unroll
      for (int s = 0; s < 4; s++) {
        float pe = __expf(sv[s] - mnew);
        psum += pe;
        Ps[wave][(q4 * 4 + rg) * 80 + s * 16 + l15] = (short)f2bf(pe);
      }
      lrow[rg] = lrow[rg] * alpha + psum;
#pragma unroll
      for (int j = 0; j < 4; j++) o[j][rg] *= alpha;
    }

    // O += P * V  (P via per-wave LDS transpose, K=32 chunks)
#pragma unroll
    for (int kc = 0; kc < 2; kc++) {
      bf16x8 pa = *(const bf16x8*)(&Ps[wave][l15 * 80 + kc * 32 + q4 * 8]);
#pragma unroll
      for (int j = 0; j < 4; j++) {
        bf16x8 vf = *(const bf16x8*)(Vs + (j * 16 + l15) * 64 + kc * 32 + q4 * 8);
        o[j] = __builtin_amdgcn_mfma_f32_16x16x32_bf16(pa, vf, o[j], 0, 0, 0);
      }
    }
  }

#pragma unroll
  for (int rg = 0; rg < 4; rg++) {
    float l = lrow[rg];
    l += __shfl_xor(l, 1);
    l += __shfl_xor(l, 2);
    l += __shfl_xor(l, 4);
    l += __shfl_xor(l, 8);
    float inv = 1.0f / l;
    int qrow = q0 + q4 * 4 + rg;
    float* op = out + (size_t)(b * SQL + qrow) * 1024 + h * DH;
#pragma unroll
    for (int j = 0; j < 4; j++) op[j * 16 + l15] = o[j][rg] * inv;
  }
}

extern "C" void kernel_launch(void* const* d_in, const int* in_sizes, int n_in,
                              void* d_out, int out_size, void* d_ws, size_t ws_size,
                              hipStream_t stream) {
  const float* x_q  = (const float*)d_in[0];
  const float* x_kv = (const float*)d_in[1];
  const int*   amask = (const int*)d_in[2];
  const float* w_q  = (const float*)d_in[3];
  const float* b_q  = (const float*)d_in[4];
  const float* w_k  = (const float*)d_in[5];
  const float* b_k  = (const float*)d_in[6];
  const float* w_v  = (const float*)d_in[7];
  const float* b_v  = (const float*)d_in[8];
  float* out = (float*)d_out;

  char* ws = (char*)d_ws;
  unsigned short* xq_bf  = (unsigned short*)(ws + 0);          // 16 MB
  unsigned short* xkv_bf = (unsigned short*)(ws + 16777216);   // 16 MB
  unsigned short* wqt    = (unsigned short*)(ws + 33554432);   // 2 MB
  unsigned short* wkt    = (unsigned short*)(ws + 35651584);   // 2 MB
  unsigned short* wvt    = (unsigned short*)(ws + 37748736);   // 2 MB
  unsigned short* Qb     = (unsigned short*)(ws + 39845888);   // 16 MB
  unsigned short* Kb     = (unsigned short*)(ws + 56623104);   // 16 MB
  unsigned short* Vtb    = (unsigned short*)(ws + 73400320);   // 16 MB
  unsigned int*   mwords = (unsigned int*)(ws + 90177536);     // 2 MB

  cvt_bf16_kernel<<<8192, 256, 0, stream>>>(x_q, xq_bf, 2097152);
  cvt_bf16_kernel<<<8192, 256, 0, stream>>>(x_kv, xkv_bf, 2097152);
  wtrans_kernel<<<dim3(32, 32, 3), 256, 0, stream>>>(w_q, w_k, w_v, wqt, wkt, wvt);
  maskpack_kernel<<<2048, 256, 0, stream>>>(amask, mwords);
  proj_gemm_kernel<0><<<dim3(8, 64), 256, 0, stream>>>(xq_bf, wqt, b_q, Qb);
  proj_gemm_kernel<0><<<dim3(8, 64), 256, 0, stream>>>(xkv_bf, wkt, b_k, Kb);
  proj_gemm_kernel<1><<<dim3(8, 64), 256, 0, stream>>>(xkv_bf, wvt, b_v, Vtb);
  attn_kernel<<<dim3(32, 64), 256, 0, stream>>>(Qb, Kb, Vtb, mwords, out);
}

// Round 3
// 396.082 us; speedup vs baseline: 1.2568x; 1.2568x over previous
//
#include <hip/hip_runtime.h>
#include <hip/hip_bf16.h>
#include <stdint.h>

#define BB 4
#define SQL 2048
#define SKL 2048
#define EMB 1024
#define NH 16
#define DH 64

typedef __bf16 bf16x8 __attribute__((ext_vector_type(8)));
typedef short s16x4 __attribute__((ext_vector_type(4)));
typedef float f32x4 __attribute__((ext_vector_type(4)));

// scale folded into Q projection: 1/sqrt(64) * log2(e)
#define QSCALE 0.1803368801111144f

__device__ __forceinline__ unsigned short f2bf(float f) {
  union { float f; uint32_t u; } v; v.f = f;
  uint32_t u = v.u;
  return (unsigned short)((u + 0x7fffu + ((u >> 16) & 1u)) >> 16);
}

typedef const __attribute__((address_space(1))) void* gas_t;
typedef __attribute__((address_space(3))) void* las_t;
__device__ __forceinline__ void gld16(const void* g, void* l) {
  __builtin_amdgcn_global_load_lds((gas_t)g, (las_t)l, 16, 0, 0);
}

// ---------------- fp32 -> bf16 convert ----------------
__global__ void cvt_bf16_kernel(const float* __restrict__ src,
                                unsigned short* __restrict__ dst, int n4) {
  int i = blockIdx.x * 256 + threadIdx.x;
  if (i >= n4) return;
  float4 v = ((const float4*)src)[i];
  ushort4 o;
  o.x = f2bf(v.x); o.y = f2bf(v.y); o.z = f2bf(v.z); o.w = f2bf(v.w);
  ((ushort4*)dst)[i] = o;
}

// ---------------- w [K][N] fp32 -> w^T [N][K] bf16 ----------------
__global__ void wtrans_kernel(const float* __restrict__ w0, const float* __restrict__ w1,
                              const float* __restrict__ w2,
                              unsigned short* __restrict__ o0, unsigned short* __restrict__ o1,
                              unsigned short* __restrict__ o2) {
  __shared__ float t[32][33];
  const float* w = blockIdx.z == 0 ? w0 : (blockIdx.z == 1 ? w1 : w2);
  unsigned short* o = blockIdx.z == 0 ? o0 : (blockIdx.z == 1 ? o1 : o2);
  int tx = threadIdx.x & 31, ty = threadIdx.x >> 5;
  int n0 = blockIdx.x * 32, k0 = blockIdx.y * 32;
#pragma unroll
  for (int r = 0; r < 4; r++)
    t[ty + r * 8][tx] = w[(size_t)(k0 + ty + r * 8) * EMB + n0 + tx];
  __syncthreads();
#pragma unroll
  for (int r = 0; r < 4; r++)
    o[(size_t)(n0 + ty + r * 8) * EMB + k0 + tx] = f2bf(t[tx][ty + r * 8]);
}

// ---------------- mask int32 -> packed bits ----------------
__global__ void maskpack_kernel(const int* __restrict__ m, unsigned int* __restrict__ words) {
  int w = blockIdx.x * 256 + threadIdx.x;
  const int4* p = (const int4*)(m + (size_t)w * 32);
  unsigned int bits = 0;
#pragma unroll
  for (int j = 0; j < 8; j++) {
    int4 v = p[j];
    bits |= (v.x != 0 ? 1u : 0u) << (j * 4 + 0);
    bits |= (v.y != 0 ? 1u : 0u) << (j * 4 + 1);
    bits |= (v.z != 0 ? 1u : 0u) << (j * 4 + 2);
    bits |= (v.w != 0 ? 1u : 0u) << (j * 4 + 3);
  }
  words[w] = bits;
}

// ---------------- fused projection GEMMs (z = 0:Q, 1:K, 2:V) ----------------
// z 0/1: out[bh][s][64] bf16 (Q pre-scaled by QSCALE).  z 2: out[bh][64][s] bf16.
__global__ __launch_bounds__(256, 2) void proj_gemm_kernel(
    const unsigned short* __restrict__ Aq, const unsigned short* __restrict__ Akv,
    const unsigned short* __restrict__ W0, const unsigned short* __restrict__ W1,
    const unsigned short* __restrict__ W2,
    const float* __restrict__ bq, const float* __restrict__ bk, const float* __restrict__ bv,
    unsigned short* __restrict__ Oq, unsigned short* __restrict__ Ok,
    unsigned short* __restrict__ Ov) {
  __shared__ short As[128 * 32];
  __shared__ short Bs[128 * 32];
  const int z = blockIdx.z;
  const unsigned short* A = (z == 0) ? Aq : Akv;
  const unsigned short* Bt = (z == 0) ? W0 : (z == 1 ? W1 : W2);
  const float* bias = (z == 0) ? bq : (z == 1 ? bk : bv);
  unsigned short* out = (z == 0) ? Oq : (z == 1 ? Ok : Ov);
  const float oscale = (z == 0) ? QSCALE : 1.0f;

  const int tid = threadIdx.x;
  const int wave = tid >> 6, lane = tid & 63;
  const int l15 = lane & 15, q4 = lane >> 4;
  const int wm = wave >> 1, wn = wave & 1;
  const int m0 = blockIdx.y * 128, n0 = blockIdx.x * 128;

  f32x4 acc[4][4];
#pragma unroll
  for (int i = 0; i < 4; i++)
#pragma unroll
    for (int j = 0; j < 4; j++) acc[i][j] = (f32x4){0.f, 0.f, 0.f, 0.f};

  const int r = tid >> 2;
  const int c = (tid & 3) * 8;
  const unsigned short* gA0 = A + (size_t)(m0 + r) * EMB + c;
  const unsigned short* gA1 = A + (size_t)(m0 + r + 64) * EMB + c;
  const unsigned short* gB0 = Bt + (size_t)(n0 + r) * EMB + c;
  const unsigned short* gB1 = Bt + (size_t)(n0 + r + 64) * EMB + c;
  short* lA0 = As + tid * 8;
  short* lA1 = As + tid * 8 + 2048;
  short* lB0 = Bs + tid * 8;
  short* lB1 = Bs + tid * 8 + 2048;

  for (int kt = 0; kt < EMB / 32; kt++) {
    __syncthreads();
    gld16(gA0 + kt * 32, lA0);
    gld16(gA1 + kt * 32, lA1);
    gld16(gB0 + kt * 32, lB0);
    gld16(gB1 + kt * 32, lB1);
    __syncthreads();
    bf16x8 a[4], b[4];
#pragma unroll
    for (int i = 0; i < 4; i++)
      a[i] = *(const bf16x8*)(As + (wm * 64 + i * 16 + l15) * 32 + q4 * 8);
#pragma unroll
    for (int j = 0; j < 4; j++)
      b[j] = *(const bf16x8*)(Bs + (wn * 64 + j * 16 + l15) * 32 + q4 * 8);
#pragma unroll
    for (int i = 0; i < 4; i++)
#pragma unroll
      for (int j = 0; j < 4; j++)
        acc[i][j] = __builtin_amdgcn_mfma_f32_16x16x32_bf16(a[i], b[j], acc[i][j], 0, 0, 0);
  }

#pragma unroll
  for (int i = 0; i < 4; i++) {
    const int mrow = m0 + wm * 64 + i * 16 + q4 * 4;
#pragma unroll
    for (int j = 0; j < 4; j++) {
      const int n = n0 + wn * 64 + j * 16 + l15;
      const float bvv = bias[n];
      const int h = n >> 6, d = n & 63;
      if (z <= 1) {
#pragma unroll
        for (int rg = 0; rg < 4; rg++) {
          int m = mrow + rg;
          int bb = m >> 11, sq = m & 2047;
          out[(size_t)((bb * NH + h) * SQL + sq) * DH + d] = f2bf((acc[i][j][rg] + bvv) * oscale);
        }
      } else {
        int bb = mrow >> 11, sq = mrow & 2047;
        ushort4 pk;
        pk.x = f2bf(acc[i][j][0] + bvv);
        pk.y = f2bf(acc[i][j][1] + bvv);
        pk.z = f2bf(acc[i][j][2] + bvv);
        pk.w = f2bf(acc[i][j][3] + bvv);
        *(ushort4*)(out + (size_t)((bb * NH + h) * DH + d) * SKL + sq) = pk;
      }
    }
  }
}

// ---------------- fused flash attention (S^T trick, no online max) ----------------
// grid (32 qtiles, 64 bh), 256 threads; wave handles 16 q rows.
// S^T = K.Q^T via mfma C-layout: lane owns (kv=q4*4+rg, q=l15)
//   == A-frag layout of 16x16x16 PV mfma (m=l15=q, k=q4*4+j=kv). No transpose needed.
// K/V LDS layouts XOR-swizzled (phys col8 = col8 ^ (row&7)) on the GLOBAL address
// side of global_load_lds, so fragment ds_reads are conflict-free.
__global__ __launch_bounds__(256, 4) void attn_kernel(
    const unsigned short* __restrict__ Qb,  // [64][2048][64] bf16 (pre-scaled)
    const unsigned short* __restrict__ Kb,  // [64][2048][64]
    const unsigned short* __restrict__ Vt,  // [64][64][2048]
    const unsigned int* __restrict__ mw,    // [4][2048][64] bit kv&31 of word kv>>5
    float* __restrict__ out) {              // [4][2048][1024]
  __shared__ short Ks[64 * 64];
  __shared__ short Vs[64 * 64];
  __shared__ float Ls[4][16];
  const int tid = threadIdx.x;
  const int wave = tid >> 6, lane = tid & 63;
  const int l15 = lane & 15, q4 = lane >> 4;
  const int bh = blockIdx.y, b = bh >> 4, h = bh & 15;
  const int q0 = blockIdx.x * 64 + wave * 16;

  // Q b-frag (n=q=l15, k=d=q4*8+j), held in regs for the whole kernel
  const unsigned short* qg = Qb + (size_t)(bh * SQL + q0 + l15) * DH + q4 * 8;
  const bf16x8 qa0 = *(const bf16x8*)qg;
  const bf16x8 qa1 = *(const bf16x8*)(qg + 32);

  f32x4 o[4];
#pragma unroll
  for (int j = 0; j < 4; j++) o[j] = (f32x4){0.f, 0.f, 0.f, 0.f};
  float lrow = 0.f;

  // staging: lane stages LDS slot tid*16B; global col8 swizzled by row&7
  const int sr = tid >> 3;
  const int gc8 = ((tid & 7) ^ (sr & 7)) * 8;
  const unsigned short* kgA = Kb + (size_t)bh * SKL * DH + sr * DH + gc8;
  const unsigned short* kgB = Kb + (size_t)bh * SKL * DH + (sr + 32) * DH + gc8;
  const unsigned short* vgA = Vt + (size_t)bh * DH * SKL + (size_t)sr * SKL + gc8;
  const unsigned short* vgB = Vt + (size_t)bh * DH * SKL + (size_t)(sr + 32) * SKL + gc8;
  short* lK0 = Ks + tid * 8; short* lK1 = Ks + 2048 + tid * 8;
  short* lV0 = Vs + tid * 8; short* lV1 = Vs + 2048 + tid * 8;

  // fragment-read swizzle constants
  const int lx = l15 & 7;
  const int kph0 = (q4 ^ lx) * 8;        // K logical col8 = q4   (d 0..31)
  const int kph1 = ((q4 + 4) ^ lx) * 8;  // K logical col8 = q4+4 (d 32..63)
  const int voff = (q4 & 1) * 4;
  const unsigned int* mrp = mw + ((size_t)b * SQL + q0 + l15) * 64;

  for (int kv0 = 0; kv0 < SKL; kv0 += 64) {
    __syncthreads();
    gld16(kgA + kv0 * DH, lK0);
    gld16(kgB + kv0 * DH, lK1);
    gld16(vgA + kv0, lV0);
    gld16(vgB + kv0, lV1);
    uint2 mk = *(const uint2*)(mrp + (kv0 >> 5));
    __syncthreads();

#pragma unroll
    for (int sub = 0; sub < 4; sub++) {
      const short* kbase = Ks + (sub * 16 + l15) * 64;
      bf16x8 af0 = *(const bf16x8*)(kbase + kph0);
      bf16x8 af1 = *(const bf16x8*)(kbase + kph1);
      f32x4 s4 = (f32x4){0.f, 0.f, 0.f, 0.f};
      s4 = __builtin_amdgcn_mfma_f32_16x16x32_bf16(af0, qa0, s4, 0, 0, 0);
      s4 = __builtin_amdgcn_mfma_f32_16x16x32_bf16(af1, qa1, s4, 0, 0, 0);

      // p = exp2(s) (Q pre-scaled), zero masked lanes, accumulate row-sum
      unsigned int mbits = ((sub & 2) ? mk.y : mk.x) >> (((sub & 1) * 16) + q4 * 4);
      float p[4];
#pragma unroll
      for (int rg = 0; rg < 4; rg++) {
        float e = __builtin_exp2f(s4[rg]);
        e = ((mbits >> rg) & 1u) ? 0.f : e;
        lrow += e;
        p[rg] = e;
      }
      // pack 4 fp32 -> 4 bf16
      union { float f; uint32_t u; } c0, c1, c2, c3;
      c0.f = p[0]; c1.f = p[1]; c2.f = p[2]; c3.f = p[3];
      uint32_t lo = ((c0.u + 0x8000u) >> 16) | ((c1.u + 0x8000u) & 0xffff0000u);
      uint32_t hi = ((c2.u + 0x8000u) >> 16) | ((c3.u + 0x8000u) & 0xffff0000u);
      uint2 ppu; ppu.x = lo; ppu.y = hi;
      s16x4 pp = __builtin_bit_cast(s16x4, ppu);

      // O[q][d] += P * V : b-frag = V^T[d=dsub*16+l15][kv=sub*16+q4*4+j]
      const int vph = ((sub * 2 + (q4 >> 1)) ^ lx) * 8 + voff;
#pragma unroll
      for (int dsub = 0; dsub < 4; dsub++) {
        s16x4 bv = *(const s16x4*)(Vs + (dsub * 16 + l15) * 64 + vph);
        o[dsub] = __builtin_amdgcn_mfma_f32_16x16x16bf16_1k(pp, bv, o[dsub], 0, 0, 0);
      }
    }
  }

  // row-sum: l[q=l15] = sum over quads
  lrow += __shfl_xor(lrow, 16);
  lrow += __shfl_xor(lrow, 32);
  if (lane < 16) Ls[wave][lane] = lrow;
  __syncthreads();

#pragma unroll
  for (int rg = 0; rg < 4; rg++) {
    const float inv = 1.0f / Ls[wave][q4 * 4 + rg];
    float* op = out + (size_t)(b * SQL + q0 + q4 * 4 + rg) * 1024 + h * DH + l15;
#pragma unroll
    for (int dsub = 0; dsub < 4; dsub++) op[dsub * 16] = o[dsub][rg] * inv;
  }
}

extern "C" void kernel_launch(void* const* d_in, const int* in_sizes, int n_in,
                              void* d_out, int out_size, void* d_ws, size_t ws_size,
                              hipStream_t stream) {
  const float* x_q  = (const float*)d_in[0];
  const float* x_kv = (const float*)d_in[1];
  const int*   amask = (const int*)d_in[2];
  const float* w_q  = (const float*)d_in[3];
  const float* b_q  = (const float*)d_in[4];
  const float* w_k  = (const float*)d_in[5];
  const float* b_k  = (const float*)d_in[6];
  const float* w_v  = (const float*)d_in[7];
  const float* b_v  = (const float*)d_in[8];
  float* out = (float*)d_out;

  char* ws = (char*)d_ws;
  unsigned short* xq_bf  = (unsigned short*)(ws + 0);
  unsigned short* xkv_bf = (unsigned short*)(ws + 16777216);
  unsigned short* wqt    = (unsigned short*)(ws + 33554432);
  unsigned short* wkt    = (unsigned short*)(ws + 35651584);
  unsigned short* wvt    = (unsigned short*)(ws + 37748736);
  unsigned short* Qb     = (unsigned short*)(ws + 39845888);
  unsigned short* Kb     = (unsigned short*)(ws + 56623104);
  unsigned short* Vtb    = (unsigned short*)(ws + 73400320);
  unsigned int*   mwords = (unsigned int*)(ws + 90177536);

  cvt_bf16_kernel<<<8192, 256, 0, stream>>>(x_q, xq_bf, 2097152);
  cvt_bf16_kernel<<<8192, 256, 0, stream>>>(x_kv, xkv_bf, 2097152);
  wtrans_kernel<<<dim3(32, 32, 3), 256, 0, stream>>>(w_q, w_k, w_v, wqt, wkt, wvt);
  maskpack_kernel<<<2048, 256, 0, stream>>>(amask, mwords);
  proj_gemm_kernel<<<dim3(8, 64, 3), 256, 0, stream>>>(
      xq_bf, xkv_bf, wqt, wkt, wvt, b_q, b_k, b_v, Qb, Kb, Vtb);
  attn_kernel<<<dim3(32, 64), 256, 0, stream>>>(Qb, Kb, Vtb, mwords, out);
}